// Round 1
// baseline (147.007 us; speedup 1.0000x reference)
//
#include <hip/hip_runtime.h>

#define N_ATOMS 2048
#define NT 256

__device__ __forceinline__ float silu_f(float x) {
    return x / (1.0f + __expf(-x));
}

// ---------------------------------------------------------------------------
// Kernel 1: per-atom RBF features. One block per atom; positions staged in LDS.
// feat[i][r] = sum_{j != i, d<5} exp(-(d-c_r)^2/(2 eta^2)) * 0.5*(1+cos(pi*d/5))
// ---------------------------------------------------------------------------
__global__ __launch_bounds__(NT) void feat_kernel(const float* __restrict__ pos,
                                                  float* __restrict__ feat) {
    __shared__ float spx[N_ATOMS], spy[N_ATOMS], spz[N_ATOMS];
    __shared__ float wsum[4][16];
    const int i = blockIdx.x;
    for (int j = threadIdx.x; j < N_ATOMS; j += NT) {
        spx[j] = pos[3*j + 0];
        spy[j] = pos[3*j + 1];
        spz[j] = pos[3*j + 2];
    }
    __syncthreads();
    const float pix = spx[i], piy = spy[i], piz = spz[i];
    float acc[16];
    #pragma unroll
    for (int r = 0; r < 16; ++r) acc[r] = 0.0f;

    for (int j = threadIdx.x; j < N_ATOMS; j += NT) {
        float dx = pix - spx[j];
        float dy = piy - spy[j];
        float dz = piz - spz[j];
        float d2 = dx*dx + dy*dy + dz*dz;
        if (d2 > 0.0f && d2 < 25.0f) {
            float d  = sqrtf(d2);
            // smooth = 0.5*(1+cos(pi*d/5))
            float sm = 0.5f * (1.0f + __cosf(0.6283185307179586f * d));
            #pragma unroll
            for (int r = 0; r < 16; ++r) {
                float c = 0.5f + 0.3f * (float)r;           // linspace(0.5, 5, 16)
                float t = d - c;
                // 1/(2*eta^2) = 2048/81 exactly (eta = 0.140625)
                acc[r] += sm * __expf(-t * t * 25.28395061728395f);
            }
        }
    }

    const int lane = threadIdx.x & 63;
    const int wave = threadIdx.x >> 6;
    #pragma unroll
    for (int r = 0; r < 16; ++r) {
        float v = acc[r];
        #pragma unroll
        for (int off = 32; off > 0; off >>= 1) v += __shfl_down(v, off, 64);
        if (lane == 0) wsum[wave][r] = v;
    }
    __syncthreads();
    if (threadIdx.x < 16) {
        feat[i * 16 + threadIdx.x] = wsum[0][threadIdx.x] + wsum[1][threadIdx.x]
                                   + wsum[2][threadIdx.x] + wsum[3][threadIdx.x];
    }
}

// ---------------------------------------------------------------------------
// Kernel 2: both MLPs (16->64->64->1, silu), one wave per (atom, which-mlp).
// 4096 wave-tasks -> 1024 blocks x 4 waves. which is uniform per block.
// Writes raw_q[atom] (charge MLP) and accumulates sum(raw_q) into acc[0],
// sum(E_sr_i) into acc[1] (one atomic per block).
// ---------------------------------------------------------------------------
__global__ __launch_bounds__(NT) void mlp_kernel(
    const float* __restrict__ feat,
    const float* __restrict__ cw1, const float* __restrict__ cb1,
    const float* __restrict__ cw2, const float* __restrict__ cb2,
    const float* __restrict__ cw3, const float* __restrict__ cb3,
    const float* __restrict__ ew1, const float* __restrict__ eb1,
    const float* __restrict__ ew2, const float* __restrict__ eb2,
    const float* __restrict__ ew3, const float* __restrict__ eb3,
    float* __restrict__ rawq, float* __restrict__ acc)
{
    const int wave  = threadIdx.x >> 6;
    const int lane  = threadIdx.x & 63;
    const int task  = blockIdx.x * 4 + wave;      // 0..4095
    const int atom  = task & (N_ATOMS - 1);
    const int which = task >> 11;                 // 0: charge MLP, 1: energy MLP (uniform per block)

    const float* w1 = which ? ew1 : cw1;
    const float* b1 = which ? eb1 : cb1;
    const float* w2 = which ? ew2 : cw2;
    const float* b2 = which ? eb2 : cb2;
    const float* w3 = which ? ew3 : cw3;
    const float* b3 = which ? eb3 : cb3;

    __shared__ float sh[4][64];
    __shared__ float sred[4];

    // layer 1: lane computes hidden unit `lane`
    float s = b1[lane];
    #pragma unroll
    for (int r = 0; r < 16; ++r)
        s += feat[atom * 16 + r] * w1[r * 64 + lane];   // feat: scalar broadcast; w1: coalesced
    sh[wave][lane] = silu_f(s);
    __syncthreads();

    // layer 2
    float s2 = b2[lane];
    #pragma unroll 8
    for (int k = 0; k < 64; ++k)
        s2 += sh[wave][k] * w2[k * 64 + lane];
    float h2 = silu_f(s2);

    // layer 3 + wave reduce
    float p = h2 * w3[lane];
    #pragma unroll
    for (int off = 32; off > 0; off >>= 1) p += __shfl_down(p, off, 64);

    if (lane == 0) {
        float out = p + b3[0];
        sred[wave] = out;
        if (which == 0) rawq[atom] = out;
    }
    __syncthreads();
    if (threadIdx.x == 0) {
        atomicAdd(&acc[which], sred[0] + sred[1] + sred[2] + sred[3]);
    }
}

// ---------------------------------------------------------------------------
// Kernel 3: E_lr pass. One block per atom i; positions + corrected charges in
// LDS. s_i = sum_{j != i} q_j / r_ij ; atomicAdd(acc[2], q_i * s_i).
// Also writes charges to d_out[1+i].
// ---------------------------------------------------------------------------
__global__ __launch_bounds__(NT) void elr_kernel(const float* __restrict__ pos,
                                                 const float* __restrict__ rawq,
                                                 const float* __restrict__ acc,
                                                 float* __restrict__ charges_out,
                                                 float* __restrict__ elr_acc)
{
    __shared__ float spx[N_ATOMS], spy[N_ATOMS], spz[N_ATOMS], sq[N_ATOMS];
    __shared__ float sred[4];
    const int i = blockIdx.x;
    const float corr = -acc[0] * (1.0f / (float)N_ATOMS);
    for (int j = threadIdx.x; j < N_ATOMS; j += NT) {
        spx[j] = pos[3*j + 0];
        spy[j] = pos[3*j + 1];
        spz[j] = pos[3*j + 2];
        sq[j]  = rawq[j] + corr;
    }
    __syncthreads();
    const float pix = spx[i], piy = spy[i], piz = spz[i];
    const float qi = sq[i];

    float s = 0.0f;
    for (int j = threadIdx.x; j < N_ATOMS; j += NT) {
        float dx = pix - spx[j];
        float dy = piy - spy[j];
        float dz = piz - spz[j];
        float d2 = dx*dx + dy*dy + dz*dz;
        if (j != i) s += sq[j] * rsqrtf(d2);
    }

    const int lane = threadIdx.x & 63;
    const int wave = threadIdx.x >> 6;
    #pragma unroll
    for (int off = 32; off > 0; off >>= 1) s += __shfl_down(s, off, 64);
    if (lane == 0) sred[wave] = s;
    __syncthreads();
    if (threadIdx.x == 0) {
        float si = sred[0] + sred[1] + sred[2] + sred[3];
        atomicAdd(elr_acc, qi * si);
        charges_out[i] = qi;
    }
}

// ---------------------------------------------------------------------------
// Kernel 4: finalize. E = 0.5 * sum_{i!=j} q_i q_j / r_ij + E_sr
// ---------------------------------------------------------------------------
__global__ void fin_kernel(const float* __restrict__ acc, float* __restrict__ out) {
    if (threadIdx.x == 0) out[0] = 0.5f * acc[2] + acc[1];
}

extern "C" void kernel_launch(void* const* d_in, const int* in_sizes, int n_in,
                              void* d_out, int out_size, void* d_ws, size_t ws_size,
                              hipStream_t stream) {
    const float* pos = (const float*)d_in[0];
    const float* cw1 = (const float*)d_in[1];
    const float* cb1 = (const float*)d_in[2];
    const float* cw2 = (const float*)d_in[3];
    const float* cb2 = (const float*)d_in[4];
    const float* cw3 = (const float*)d_in[5];
    const float* cb3 = (const float*)d_in[6];
    const float* ew1 = (const float*)d_in[7];
    const float* eb1 = (const float*)d_in[8];
    const float* ew2 = (const float*)d_in[9];
    const float* eb2 = (const float*)d_in[10];
    const float* ew3 = (const float*)d_in[11];
    const float* eb3 = (const float*)d_in[12];
    float* out = (float*)d_out;

    // workspace layout
    float* feat = (float*)d_ws;                 // 2048*16
    float* rawq = feat + N_ATOMS * 16;          // 2048
    float* acc  = rawq + N_ATOMS;               // [0]=sum(raw_q) [1]=E_sr [2]=2*E_lr

    hipMemsetAsync(acc, 0, 3 * sizeof(float), stream);
    feat_kernel<<<N_ATOMS, NT, 0, stream>>>(pos, feat);
    mlp_kernel<<<1024, NT, 0, stream>>>(feat,
                                        cw1, cb1, cw2, cb2, cw3, cb3,
                                        ew1, eb1, ew2, eb2, ew3, eb3,
                                        rawq, acc);
    elr_kernel<<<N_ATOMS, NT, 0, stream>>>(pos, rawq, acc, out + 1, acc + 2);
    fin_kernel<<<1, 64, 0, stream>>>(acc, out);
}